// Round 1
// baseline (141.377 us; speedup 1.0000x reference)
//
#include <hip/hip_runtime.h>

constexpr int Bn = 8, S = 2048, E = 1024, H = 64;
// E^-0.5 * log2(e) folded into q: scores come out of QK^T already in log2
// domain, so softmax is exp2f(s - m) with no per-element LOG2E multiply.
constexpr float SCALE = 0.03125f * 1.44269504f;

typedef __attribute__((ext_vector_type(8))) short short8;  // 8 bf16
typedef __attribute__((ext_vector_type(4))) float f32x4;   // MFMA C/D

__device__ __forceinline__ unsigned short f2bf(float f) {
  unsigned u = __builtin_bit_cast(unsigned, f);
  u += 0x7fffu + ((u >> 16) & 1u);    // RNE
  return (unsigned short)(u >> 16);
}
__device__ __forceinline__ ushort4 f4bf(float4 f) {
  return make_ushort4(f2bf(f.x), f2bf(f.y), f2bf(f.z), f2bf(f.w));
}

// ---------- W [1024][64] fp32 -> WT3 [3][64][1024] bf16 ----------
__global__ __launch_bounds__(256) void wtrans_kernel(
    const float* __restrict__ Wq, const float* __restrict__ Wk,
    const float* __restrict__ Wv, unsigned short* __restrict__ WT3) {
  __shared__ unsigned short tb[64][72];
  const int m = blockIdx.x >> 4;
  const int e0 = (blockIdx.x & 15) * 64;
  const float* W = (m == 0) ? Wq : (m == 1) ? Wk : Wv;
  const int t = threadIdx.x;
#pragma unroll
  for (int it = 0; it < 4; ++it) {
    int idx = t + it * 256;
    int r = idx >> 4, c4 = idx & 15;
    float4 f = ((const float4*)(W + (long)(e0 + r) * H))[c4];
    *(ushort4*)&tb[r][c4 * 4] = f4bf(f);
  }
  __syncthreads();
#pragma unroll
  for (int it = 0; it < 4; ++it) {
    int idx = t + it * 256;
    int h = idx >> 4, e4 = idx & 15;
    ushort4 u = make_ushort4(tb[e4 * 4 + 0][h], tb[e4 * 4 + 1][h],
                             tb[e4 * 4 + 2][h], tb[e4 * 4 + 3][h]);
    ((ushort4*)(WT3 + (long)(m * 64 + h) * E + e0))[e4] = u;
  }
}

// ---------- QKV GEMM, m97-style: M=32 x N=192, BK=128, LDS-dense ----------
__global__ __launch_bounds__(256) void qkv_kernel(
    const float* __restrict__ x, const unsigned short* __restrict__ WT3,
    unsigned short* __restrict__ q, unsigned short* __restrict__ kk,
    unsigned short* __restrict__ vT) {
  __shared__ unsigned short xs[32][136];    // [seq-row][e in chunk]
  __shared__ unsigned short ws[192][136];   // [out-col j][e in chunk]
  const int t = threadIdx.x;
  const int w = t >> 6, lane = t & 63, l15 = lane & 15, g = lane >> 4;
  const long row0 = (long)blockIdx.x * 32;
  const int xrow = t >> 5, xslot = t & 31;  // x: 8 rows x 32 float4 / iter
  const int wrow = t >> 4, wslot = t & 15;  // W: 16 rows x 16 short8 / iter

  f32x4 acc[2][3];
#pragma unroll
  for (int rt = 0; rt < 2; ++rt)
#pragma unroll
    for (int ct = 0; ct < 3; ++ct) acc[rt][ct] = f32x4{0.f, 0.f, 0.f, 0.f};

  float4 px[4];
  short8 pw[12];
  // prologue: chunk 0 -> regs -> LDS
#pragma unroll
  for (int it = 0; it < 4; ++it)
    px[it] = ((const float4*)(x + (row0 + xrow + it * 8) * E))[xslot];
#pragma unroll
  for (int it = 0; it < 12; ++it)
    pw[it] = *(const short8*)(WT3 + (long)(wrow + it * 16) * E + wslot * 8);
#pragma unroll
  for (int it = 0; it < 4; ++it)
    *(ushort4*)&xs[xrow + it * 8][xslot * 4] = f4bf(px[it]);
#pragma unroll
  for (int it = 0; it < 12; ++it)
    *(short8*)&ws[wrow + it * 16][wslot * 8] = pw[it];

  for (int c = 0; c < 8; ++c) {             // 8 chunks of 128 e
    __syncthreads();                        // staged chunk visible
    if (c < 7) {                            // dense prefetch of chunk c+1
      const int e0 = (c + 1) * 128;
#pragma unroll
      for (int it = 0; it < 4; ++it)
        px[it] = ((const float4*)(x + (row0 + xrow + it * 8) * E + e0))[xslot];
#pragma unroll
      for (int it = 0; it < 12; ++it)
        pw[it] = *(const short8*)(WT3 + (long)(wrow + it * 16) * E + e0 + wslot * 8);
    }
#pragma unroll
    for (int kh = 0; kh < 4; ++kh) {
      short8 a0 = *(const short8*)&xs[l15][kh * 32 + g * 8];
      short8 a1 = *(const short8*)&xs[16 + l15][kh * 32 + g * 8];
#pragma unroll
      for (int ct = 0; ct < 3; ++ct) {
        short8 b = *(const short8*)&ws[w * 48 + ct * 16 + l15][kh * 32 + g * 8];
        acc[0][ct] = __builtin_amdgcn_mfma_f32_16x16x32_bf16(a0, b, acc[0][ct], 0, 0, 0);
        acc[1][ct] = __builtin_amdgcn_mfma_f32_16x16x32_bf16(a1, b, acc[1][ct], 0, 0, 0);
      }
    }
    __syncthreads();                        // LDS reads done
    if (c < 7) {
#pragma unroll
      for (int it = 0; it < 4; ++it)
        *(ushort4*)&xs[xrow + it * 8][xslot * 4] = f4bf(px[it]);
#pragma unroll
      for (int it = 0; it < 12; ++it)
        *(short8*)&ws[wrow + it * 16][wslot * 8] = pw[it];
    }
  }

  const int bb = (int)(row0 >> 11);
  const int srow = (int)(row0 & 2047);
#pragma unroll
  for (int ct = 0; ct < 3; ++ct) {
    const int col = w * 48 + ct * 16 + l15;
    const int mm = col >> 6, ch = col & 63;
#pragma unroll
    for (int rt = 0; rt < 2; ++rt) {
      const int srl = rt * 16 + g * 4;
      if (mm == 0) {
#pragma unroll
        for (int r = 0; r < 4; ++r)
          q[(row0 + srl + r) * H + ch] = f2bf(acc[rt][ct][r] * SCALE);
      } else if (mm == 1) {
#pragma unroll
        for (int r = 0; r < 4; ++r)
          kk[(row0 + srl + r) * H + ch] = f2bf(acc[rt][ct][r]);
      } else {
        ushort4 v4 = make_ushort4(f2bf(acc[rt][ct][0]), f2bf(acc[rt][ct][1]),
                                  f2bf(acc[rt][ct][2]), f2bf(acc[rt][ct][3]));
        *(ushort4*)(vT + ((long)bb * H + ch) * S + srow + srl) = v4;
      }
    }
  }
}

// ---------- causal flash attention, S^T formulation, balanced waves -------
// Block p owns q-tiles {p, 127-p}. The CONCATENATED K64-tile list of both
// q-tiles (nt0+nt1 == 33 for every p) is split stride-4 across all 4 waves:
// every wave in every block does exactly 8-9 tiles (old scheme: per-qt
// K-parity split -> worst wave 16 tiles, grid tail set by p=0 blocks).
// Each wave keeps two (m,l,O) states (ph-unrolled, register-resident);
// 4-way LDS merge per q-tile at the end. Scores arrive in log2 domain
// (LOG2E folded into q), so softmax is exp2f(s-m) directly.
__global__ __launch_bounds__(256, 2) void attn_kernel(
    const unsigned short* __restrict__ q, const unsigned short* __restrict__ k,
    const unsigned short* __restrict__ vT, float* __restrict__ out) {
  __shared__ unsigned short pl[4][16][72];  // per-wave P^T [qrow][key]
  __shared__ float Om[2][4][64][17];        // partial O^T [ph][wave][h][qrow]
  __shared__ float ms[2][4][16], ls[2][4][16];
  const int t = threadIdx.x;
  const int w = t >> 6, lane = t & 63, l15 = lane & 15, g = lane >> 4;
  const int b = blockIdx.x & 7, p = blockIdx.x >> 3;
  const unsigned short* kb = k + (long)b * S * H;
  const unsigned short* vb = vT + (long)b * H * S;

  const int qt0 = p, qt1 = 127 - p;
  const int nt0 = (qt0 >> 2) + 1;           // == (16*qt+79)>>6
  const int nt1 = (qt1 >> 2) + 1;
  const int qtA[2] = {qt0, qt1};
  const int ntA[2] = {nt0, nt1};
  // wave w takes indices == w (mod 4) of the concatenated tile list; the
  // phase-1 start offset continues that list: j0 = (w - nt0) mod 4.
  const int k0A[2] = {w, (w + 4 - (nt0 & 3)) & 3};

  short8 bq0[2], bq1[2];
  f32x4 O[2][4];
  float m_[2], l_[2];
#pragma unroll
  for (int ph = 0; ph < 2; ++ph) {
    const unsigned short* qp = q + ((long)b * S + qtA[ph] * 16 + l15) * H + g * 8;
    bq0[ph] = *(const short8*)qp;           // Q B-frags: n=l15=qrow, k=h
    bq1[ph] = *(const short8*)(qp + 32);
    m_[ph] = -1e30f;
    l_[ph] = 0.f;
#pragma unroll
    for (int c = 0; c < 4; ++c) O[ph][c] = f32x4{0.f, 0.f, 0.f, 0.f};
  }

#pragma unroll
  for (int ph = 0; ph < 2; ++ph) {
    const int qrow0 = qtA[ph] * 16;
    const int ntp = ntA[ph];
    short8 ak[4][2];
    int kt = k0A[ph];
    if (kt < ntp) {                         // prologue K frags
#pragma unroll
      for (int c = 0; c < 4; ++c)
#pragma unroll
        for (int kh = 0; kh < 2; ++kh)
          ak[c][kh] = *(const short8*)(kb + (long)(kt * 64 + c * 16 + l15) * H + kh * 32 + g * 8);
    }
    for (; kt < ntp; kt += 4) {
      // V^T A-frags issued early (consumed at the end of the iteration)
      short8 av[4][2];
#pragma unroll
      for (int c = 0; c < 4; ++c)
#pragma unroll
        for (int kh = 0; kh < 2; ++kh)
          av[c][kh] = *(const short8*)(vb + (long)(c * 16 + l15) * S + kt * 64 + kh * 32 + g * 8);
      // ---- S^T = K Q^T : D[m=key][n=qrow], already in log2 units ----
      f32x4 sc[4];
#pragma unroll
      for (int c = 0; c < 4; ++c) {
        sc[c] = f32x4{0.f, 0.f, 0.f, 0.f};
        sc[c] = __builtin_amdgcn_mfma_f32_16x16x32_bf16(ak[c][0], bq0[ph], sc[c], 0, 0, 0);
        sc[c] = __builtin_amdgcn_mfma_f32_16x16x32_bf16(ak[c][1], bq1[ph], sc[c], 0, 0, 0);
      }
      // prefetch K frags for kt+4
      if (kt + 4 < ntp) {
#pragma unroll
        for (int c = 0; c < 4; ++c)
#pragma unroll
          for (int kh = 0; kh < 2; ++kh)
            ak[c][kh] = *(const short8*)(kb + (long)((kt + 4) * 64 + c * 16 + l15) * H + kh * 32 + g * 8);
      }
      if (kt == ntp - 1) {                  // diagonal tile: mask key > qrow
#pragma unroll
        for (int c = 0; c < 4; ++c)
#pragma unroll
          for (int r = 0; r < 4; ++r)
            if (kt * 64 + c * 16 + g * 4 + r > qrow0 + l15) sc[c][r] = -1e30f;
      }
      // ---- per-lane softmax: local ops + 2 shuffles each for max/sum ----
      float mx = -1e30f;
#pragma unroll
      for (int c = 0; c < 4; ++c)
#pragma unroll
        for (int r = 0; r < 4; ++r) mx = fmaxf(mx, sc[c][r]);
      mx = fmaxf(mx, __shfl_xor(mx, 16));
      mx = fmaxf(mx, __shfl_xor(mx, 32));
      float mn = fmaxf(m_[ph], mx);
      float al = exp2f(m_[ph] - mn);
      float sum = 0.f;
#pragma unroll
      for (int c = 0; c < 4; ++c)
#pragma unroll
        for (int r = 0; r < 4; ++r) {
          float pe = exp2f(sc[c][r] - mn);
          sc[c][r] = pe;
          sum += pe;
        }
      sum += __shfl_xor(sum, 16);
      sum += __shfl_xor(sum, 32);
      l_[ph] = l_[ph] * al + sum;
      m_[ph] = mn;
      // ---- P^T -> per-wave LDS, O^T *= al ----
#pragma unroll
      for (int c = 0; c < 4; ++c) {
        ushort4 p4 = make_ushort4(f2bf(sc[c][0]), f2bf(sc[c][1]),
                                  f2bf(sc[c][2]), f2bf(sc[c][3]));
        *(ushort4*)&pl[w][l15][c * 16 + g * 4] = p4;
      }
#pragma unroll
      for (int c = 0; c < 4; ++c)
#pragma unroll
        for (int r = 0; r < 4; ++r) O[ph][c][r] *= al;
      // ---- O^T += V^T P^T ----
      short8 bp0 = *(const short8*)&pl[w][l15][g * 8];
      short8 bp1 = *(const short8*)&pl[w][l15][32 + g * 8];
#pragma unroll
      for (int c = 0; c < 4; ++c) {
        O[ph][c] = __builtin_amdgcn_mfma_f32_16x16x32_bf16(av[c][0], bp0, O[ph][c], 0, 0, 0);
        O[ph][c] = __builtin_amdgcn_mfma_f32_16x16x32_bf16(av[c][1], bp1, O[ph][c], 0, 0, 0);
      }
    }
  }

  // ---- 4-way merge per q-tile ----
#pragma unroll
  for (int ph = 0; ph < 2; ++ph) {
#pragma unroll
    for (int c = 0; c < 4; ++c)
#pragma unroll
      for (int r = 0; r < 4; ++r)
        Om[ph][w][c * 16 + g * 4 + r][l15] = O[ph][c][r];
    if (g == 0) { ms[ph][w][l15] = m_[ph]; ls[ph][w][l15] = l_[ph]; }
  }
  __syncthreads();
  if (w < 2) {
    const int ph = w;                       // wave 0 -> qt0, wave 1 -> qt1
    float mm0 = ms[ph][0][l15], mm1 = ms[ph][1][l15];
    float mm2 = ms[ph][2][l15], mm3 = ms[ph][3][l15];
    float mstar = fmaxf(fmaxf(mm0, mm1), fmaxf(mm2, mm3));
    float f0 = exp2f(mm0 - mstar), f1 = exp2f(mm1 - mstar);
    float f2 = exp2f(mm2 - mstar), f3 = exp2f(mm3 - mstar);
    float inv = 1.0f / (ls[ph][0][l15] * f0 + ls[ph][1][l15] * f1 +
                        ls[ph][2][l15] * f2 + ls[ph][3][l15] * f3);
    float* op = out + ((long)b * S + qtA[ph] * 16 + l15) * H;
#pragma unroll
    for (int c = 0; c < 4; ++c) {
      float o4[4];
#pragma unroll
      for (int r = 0; r < 4; ++r) {
        const int h = c * 16 + g * 4 + r;
        o4[r] = (Om[ph][0][h][l15] * f0 + Om[ph][1][h][l15] * f1 +
                 Om[ph][2][h][l15] * f2 + Om[ph][3][h][l15] * f3) * inv;
      }
      *(float4*)(op + c * 16 + g * 4) = make_float4(o4[0], o4[1], o4[2], o4[3]);
    }
  }
}

extern "C" void kernel_launch(void* const* d_in, const int* in_sizes, int n_in,
                              void* d_out, int out_size, void* d_ws, size_t ws_size,
                              hipStream_t stream) {
  const float* x  = (const float*)d_in[0];
  const float* Wq = (const float*)d_in[1];
  const float* Wk = (const float*)d_in[2];
  const float* Wv = (const float*)d_in[3];
  float* outp = (float*)d_out;
  unsigned short* WT3 = (unsigned short*)d_ws;                       // 384 KB
  unsigned short* q  = (unsigned short*)((char*)d_ws + 512 * 1024);  // 2 MB each
  unsigned short* kk = q + (size_t)Bn * S * H;
  unsigned short* vT = kk + (size_t)Bn * S * H;
  wtrans_kernel<<<dim3(48), dim3(256), 0, stream>>>(Wq, Wk, Wv, WT3);
  qkv_kernel<<<dim3((Bn * S) / 32), dim3(256), 0, stream>>>(x, WT3, q, kk, vT);
  attn_kernel<<<dim3(Bn * 64), dim3(256), 0, stream>>>(q, kk, vT, outp);
}